// Round 2
// baseline (88.494 us; speedup 1.0000x reference)
//
#include <hip/hip_runtime.h>
#include <math.h>

#define NT_ 365
#define NS_ 1024
#define NH_ 64
#define NG_ 32
#define NW_ 514        // NH*8 + 2
#define CH_ 64         // timesteps per chunk (= wave size)
#define NCHUNK_ 6      // ceil(365/64); tail steps are harmless dummies
#define YPAD_ 65       // padded row stride: bank = (lane+j)%32, conflict-free R/W
#define SUB_ 8         // met sub-chunk: register double-buffer depth

__device__ __forceinline__ float sigmoidf(float v) {
  return 1.0f / (1.0f + expf(-v));
}

// met = (Ps, Pl, relu(Ta), E); relu folded here since gm > 0
__device__ __forceinline__ float4 compute_met(float4 xv) {
  const float P = xv.x, E = xv.y, T1 = xv.z, T2 = xv.w;
  const float Ta = (T1 + T2) * 0.5f;
  float rP;
  if (T2 <= 0.0f) {
    rP = 0.0f;
  } else if (T1 >= 0.0f) {
    rP = 1.0f;
  } else {
    float r = (T1 + T2) / (T2 - T1);
    r = fminf(fmaxf(r, -0.999999f), 0.999999f);
    rP = 1.0f - acosf(r) * (1.0f / 3.1415f);
  }
  float4 m;
  m.x = (1.0f - rP) * P;   // Ps
  m.y = rP * P;            // Pl
  m.z = fmaxf(Ta, 0.0f);   // relu(Ta)
  m.w = E;
  return m;
}

// One wave per site (1024 waves -> 1 wave/SIMD machine-wide): a pure
// latency-bound serial scan, so wall time = 365 * recurrent-chain latency.
// This version cuts the cross-step H0->H0 dependence chain from 9 VALU ops
// to 4:
//   z  = H0 + dSm                          (dSm precomputed 1 step ahead)
//   H0' = min(max3(omg*z, z - gogl, 0), gl)
// using H - go*min(H,gl) == max(H*(1-go), H - go*gl) for go in (0,1), gl>0,
// and max(max(a,b),0) -> v_max3_f32. The snow branch (S0/Sm -> dSm) depends
// only on met, so it is software-pipelined one step ahead, off the critical
// path. G is a 1-fmaf linear recurrence. Instruction count per step is
// unchanged (~17 VALU) — this round isolates the chain-length effect.
__global__ __launch_bounds__(256) void waternet_scan(
    const float* __restrict__ x,     // [NT, NS, 4]
    const float* __restrict__ xc,    // [NS, NG]
    const float* __restrict__ fc_w,  // [NW, NG]
    const float* __restrict__ fc_b,  // [NW]
    float* __restrict__ out)         // [NT, NS]
{
  __shared__ float4 smet[4][CH_];          // 4 KB:  [wave][step] met
  __shared__ float  ytile[4][CH_ * YPAD_]; // 66.6 KB: per-wave y rows

  const int tid  = threadIdx.x;
  const int lane = tid & 63;
  const int wv   = tid >> 6;
  const int site = (blockIdx.x << 2) + wv;
  const int us   = __builtin_amdgcn_readfirstlane(site);
  const float4* xp = (const float4*)x;

  // chunk-0 prefetch first: HBM latency hides under the gate GEMM
  float4 xcur = xp[lane * NS_ + site];  // t = lane

  // ---- prologue GEMM: w[site, j] = xc[site,:] . fc_w[j,:] + fc_b[j]
  float acc[8];
#pragma unroll
  for (int k = 0; k < 8; ++k) acc[k] = fc_b[k * NH_ + lane];
  float accq = fc_b[NW_ - 1];

  const float4* xcq = (const float4*)(xc + us * NG_);
  const float4* wq4 = (const float4*)fc_w;
#pragma unroll
  for (int g4 = 0; g4 < NG_ / 4; ++g4) {
    const float4 xv = xcq[g4];
#pragma unroll
    for (int k = 0; k < 8; ++k) {
      const float4 w = wq4[(k * NH_ + lane) * (NG_ / 4) + g4];
      acc[k] = fmaf(xv.x, w.x, acc[k]);
      acc[k] = fmaf(xv.y, w.y, acc[k]);
      acc[k] = fmaf(xv.z, w.z, acc[k]);
      acc[k] = fmaf(xv.w, w.w, acc[k]);
    }
    {
      const float4 w = wq4[(NW_ - 1) * (NG_ / 4) + g4];
      accq = fmaf(xv.x, w.x, accq);
      accq = fmaf(xv.y, w.y, accq);
      accq = fmaf(xv.z, w.z, accq);
      accq = fmaf(xv.w, w.w, accq);
    }
  }

  // ---- gates (per-lane = per hidden unit)
  const float gm = expf(acc[0]) + 1.0f;
  const float ge = sigmoidf(acc[1]) * 2.0f;
  const float go = sigmoidf(acc[2]);
  const float gl = expf(acc[3] * 2.0f);
  float mx = acc[4];
#pragma unroll
  for (int mm = 32; mm >= 1; mm >>= 1) mx = fmaxf(mx, __shfl_xor(mx, mm, 64));
  const float ex = expf(acc[4] - mx);
  float sm = ex;
#pragma unroll
  for (int mm = 32; mm >= 1; mm >>= 1) sm += __shfl_xor(sm, mm, 64);
  const float ga = ex / sm;
  const float gb = sigmoidf(acc[5]);
  const float kb = sigmoidf(acc[6]) * 0.1f;
  const float gi = sigmoidf(acc[7]);
  const float qb = fmaxf(accq, 0.0f) * (1.0f / NH_);
  const float kb1m = 1.0f - kb;                 // G' = kb1m*G + gbgo*M
  const float nge  = -ge;
  const float gq1  = go * (1.0f - gb) - 1.0f;   // y = ga*(H + M*gq1 + G*kb)
  const float omg  = 1.0f - go;                 // H*(1-go)   branch of H0'
  const float gogl = go * gl;                   // H - go*gl  branch of H0'
  const float gbgo = gb * go;                   // G feed: gb*Q2a = gbgo*M

  // ---- scan state (dSm is the 1-step-ahead pipelined snow/forcing term)
  float S0 = 0.0f, H0 = 0.0f, G = 0.0f, dSm = 0.0f;

  // stage chunk-0 met (lane = step); per-wave slice + in-order DS -> no barrier
  smet[wv][lane] = compute_met(xcur);

  // advances the S-chain for met index t and produces dSm_t from S0_{t-1}.
  // Called exactly once per timestep: chunk-top for local step 0, then each
  // h_step pre-stages the NEXT step. Off the H critical path (S-chain depth 3).
  auto s_stage = [&](const float4 m) {
    const float melt = m.z * gm;          // relu(Ta)*gm
    const float Sm   = fminf(S0, melt);
    const float e1   = fmaf(m.w, nge, Sm);   // Sm - E*ge
    dSm = fmaf(m.y, gi, e1);                 // + Pl*gi
    S0  = (S0 - Sm) + m.x;                   // + Ps
  };

  // recurrent path: z -> {omg*z, z-gogl} -> max3 -> min  (4 dependent ops)
  auto h_step = [&](float* ywaddr) {
    const float z = H0 + dSm;
    const float a = z * omg;
    const float b = z - gogl;
    H0 = fminf(fmaxf(fmaxf(a, b), 0.0f), gl);   // v_max3_f32 + v_min_f32
    const float Hh = fmaxf(z, 0.0f);
    const float M  = fminf(Hh, gl);
    G = fmaf(kb1m, G, gbgo * M);                // G_t = kb1m*G + gb*go*M
    *ywaddr = ga * fmaf(kb, G, fmaf(gq1, M, Hh));
  };

  float*       yw = &ytile[wv][lane];          // step j writes yw[j*YPAD_]
  const float* yr = &ytile[wv][lane * YPAD_];  // reduce: lane sums its row

#pragma unroll 1   // keep body I-cache resident across 6 iterations
  for (int c = 0; c < NCHUNK_; ++c) {
    // prefetch chunk c+1 from HBM (clamped dummy tail) — in flight all chunk
    int tn = (c + 1) * CH_ + lane;
    tn = (tn < NT_) ? tn : (NT_ - 1);
    const float4 xnext = xp[tn * NS_ + site];

    const float4* mp = &smet[wv][0];

    // ---- 8-step register double-buffer: loads for sub-chunk k+1 issue
    // before sub-chunk k's compute -> ds_read latency fully covered.
    float4 mb0[SUB_], mb1[SUB_];
#pragma unroll
    for (int u = 0; u < SUB_; ++u) mb0[u] = mp[u];

    // pipeline fill: dSm/S0 for this chunk's first step (met local index 0)
    s_stage(mb0[0]);

#pragma unroll
    for (int sc = 0; sc < CH_ / SUB_; ++sc) {
      float4*       cur = (sc & 1) ? mb1 : mb0;
      float4*       nxt = (sc & 1) ? mb0 : mb1;
      if (sc < CH_ / SUB_ - 1) {
#pragma unroll
        for (int u = 0; u < SUB_; ++u) nxt[u] = mp[SUB_ * (sc + 1) + u];
      }
#pragma unroll
      for (int u = 0; u < SUB_; ++u) {
        h_step(yw + (SUB_ * sc + u) * YPAD_);
        // pre-stage NEXT step's dSm/S0 (met local index 8*sc+u+1);
        // the chunk's last step defers to the next chunk-top s_stage.
        if (u < SUB_ - 1)                     s_stage(cur[u + 1]);
        else if (sc < CH_ / SUB_ - 1)         s_stage(nxt[0]);
      }
    }

    // ---- transposed reduction: lane t' sums row t' (bank=(t'+h)%32, free)
    float r0 = 0.0f, r1 = 0.0f, r2 = 0.0f, r3 = 0.0f;
#pragma unroll
    for (int h = 0; h < CH_; h += 4) {
      r0 += yr[h + 0];
      r1 += yr[h + 1];
      r2 += yr[h + 2];
      r3 += yr[h + 3];
    }
    const int t_out = c * CH_ + lane;
    if (t_out < NT_) out[t_out * NS_ + site] = ((r0 + r1) + (r2 + r3)) + qb;

    // stage next chunk's met (reads above already issued -> in-order safe)
    if (c + 1 < NCHUNK_) smet[wv][lane] = compute_met(xnext);
  }
}

extern "C" void kernel_launch(void* const* d_in, const int* in_sizes, int n_in,
                              void* d_out, int out_size, void* d_ws, size_t ws_size,
                              hipStream_t stream) {
  const float* x    = (const float*)d_in[0];
  const float* xc   = (const float*)d_in[1];
  const float* fc_w = (const float*)d_in[2];
  const float* fc_b = (const float*)d_in[3];
  float* out = (float*)d_out;

  // 1024 sites, one wave each; 4 waves/block -> 256 blocks, 1 wave/SIMD
  // across the full machine (sites == SIMDs, so this is the max spread).
  hipLaunchKernelGGL(waternet_scan, dim3(NS_ / 4), dim3(256), 0, stream,
                     x, xc, fc_w, fc_b, out);
}